// Round 3
// baseline (248.274 us; speedup 1.0000x reference)
//
#include <hip/hip_runtime.h>
#include <hip/hip_bf16.h>

typedef unsigned short u16;
typedef unsigned int u32;
typedef __attribute__((ext_vector_type(8))) short bh8;   // 8 bf16 (MFMA A/B frag)
typedef __attribute__((ext_vector_type(4))) short sh4;   // 4 bf16 (8B store)
typedef __attribute__((ext_vector_type(4))) float f4;    // MFMA C/D frag

#define T_   4
#define B_   16
#define C_   512
#define N_   256
#define M2_  4096

// ---------------- helpers ----------------
__device__ __forceinline__ u16 f2bf(float f) {
  u32 u = __float_as_uint(f);
  u32 r = (u + 0x7FFFu + ((u >> 16) & 1u)) >> 16;   // RNE
  return (u16)r;
}
__device__ __forceinline__ void gl_lds16(const void* g, void* l) {
  __builtin_amdgcn_global_load_lds(
      (const __attribute__((address_space(1))) unsigned int*)g,
      (__attribute__((address_space(3))) unsigned int*)l, 16, 0, 0);
}

// ---------------- K0: weight hi/lo split + BN constants (merged) ----------------
__global__ void k_prep(const float* __restrict__ wq, const float* __restrict__ wk,
                       const float* __restrict__ wv, const float* __restrict__ wp,
                       const float* qg, const float* qb, const float* qm, const float* qv,
                       const float* kg, const float* kb, const float* km, const float* kv2,
                       const float* vg, const float* vb, const float* vm, const float* vv,
                       const float* pg, const float* pb, const float* pm, const float* pv,
                       const float* bp,
                       u16* __restrict__ wcat, u16* __restrict__ wpcat,
                       float* bns, float* pss) {
  int id = blockIdx.x * 256 + threadIdx.x;
  if (id < 1048576) {
    int mat = id >> 18;
    int rc  = id & 262143;
    int o = rc >> 9, c = rc & 511;
    const float* src = (mat == 0) ? wq : (mat == 1) ? wk : (mat == 2) ? wv : wp;
    float w = src[rc];
    u16 hu = f2bf(w);
    float hf = __uint_as_float(((u32)hu) << 16);
    u16 lu = f2bf(w - hf);
    if (mat < 3) {
      size_t base = ((size_t)(mat * 512 + o)) * 1024 + c;
      wcat[base] = hu; wcat[base + 512] = lu;
    } else {
      size_t base = (size_t)o * 1024 + c;
      wpcat[base] = hu; wpcat[base + 512] = lu;
    }
  } else {
    int j = id - 1048576;
    if (j < 1536) {
      int br = j >> 9, c = j & 511;
      const float *g, *b, *m, *va;
      if (br == 0)      { g = qg; b = qb; m = qm; va = qv; }
      else if (br == 1) { g = kg; b = kb; m = km; va = kv2; }
      else              { g = vg; b = vb; m = vm; va = vv; }
      float s = g[c] / sqrtf(va[c] + 1e-5f);
      bns[j * 4 + 0] = s; bns[j * 4 + 1] = m[c]; bns[j * 4 + 2] = b[c];
      bns[j * 4 + 3] = 0.f;
    } else if (j < 2048) {
      int c = j - 1536;
      float s = pg[c] / sqrtf(pv[c] + 1e-5f);
      pss[c * 4 + 0] = bp[c]; pss[c * 4 + 1] = pm[c];
      pss[c * 4 + 2] = s;     pss[c * 4 + 3] = pb[c];
    }
  }
}

// ---------------- K1: shortcut LIF + (c,n)->(n,c) transpose, bf16 spikes ----------------
__global__ void k_lif_x(const float* __restrict__ x, u16* __restrict__ xs) {
  __shared__ u16 sp[4][64][68];
  int b = blockIdx.z, c0 = blockIdx.y * 64, n0 = blockIdx.x * 64;
  int tid = threadIdx.x;
  int rq = tid >> 4;
  int n4 = (tid & 15) * 4;
  float v[16];
#pragma unroll
  for (int i = 0; i < 16; i++) v[i] = 0.f;
  for (int t = 0; t < 4; t++) {
    const float* xb = x + (((size_t)t * 16 + b) * 512 + c0) * 256 + n0;
#pragma unroll
    for (int i = 0; i < 4; i++) {
      int row = rq + i * 16;
      f4 xv = *(const f4*)(xb + (size_t)row * 256 + n4);
      sh4 sv;
#pragma unroll
      for (int j = 0; j < 4; j++) {
        float vv = v[i * 4 + j];
        vv = vv + (xv[j] - vv) * 0.5f;
        u16 s = 0;
        if (vv >= 1.0f) { s = 0x3F80; vv = 0.f; }
        v[i * 4 + j] = vv;
        sv[j] = (short)s;
      }
      *(sh4*)&sp[t][row][n4] = sv;
    }
  }
  __syncthreads();
  int cp = (tid & 31) * 2;
  int nq = tid >> 5;
  for (int t = 0; t < 4; t++) {
    u16* ob = xs + (((size_t)t * 16 + b) * 256 + n0) * 512 + c0;
#pragma unroll
    for (int i = 0; i < 8; i++) {
      int n = nq + i * 8;
      u32 w = (u32)sp[t][cp][n] | ((u32)sp[t][cp + 1][n] << 16);
      *(u32*)(ob + (size_t)n * 512 + cp) = w;
    }
  }
}

// ---------------- K2: fused QKV GEMM + BN + LIF, counted-vmcnt double-buffer ----------------
// 128x96 tile, BK=64, 32 flattened (t,ks) steps, dbuf LDS 2x40KB.
__launch_bounds__(256, 2)
__global__ void k_qkv_gemm(const u16* __restrict__ xs, const u16* __restrict__ wcat,
                           const float* __restrict__ bns,
                           u16* __restrict__ qs, u16* __restrict__ kvsp,
                           float* __restrict__ vout) {
  __shared__ char lds[81920];   // buf: A 16K | Bh 12K | Bl 12K ; x2
  int tid = threadIdx.x, lane = tid & 63, wid = tid >> 6;
  int wr = wid >> 1, wc = wid & 1, lr = lane & 15, lq = lane >> 4;
  int m0 = blockIdx.x * 128, o0 = blockIdx.y * 96;

  float scl[3], mn[3], bt[3];
#pragma unroll
  for (int ni = 0; ni < 3; ni++) {
    int ch = o0 + wc * 48 + ni * 16 + lr;
    scl[ni] = bns[ch * 4]; mn[ni] = bns[ch * 4 + 1]; bt[ni] = bns[ch * 4 + 2];
  }

  int srow = tid >> 3;
  u32 sgoff = (u32)(((tid & 7) ^ (srow & 7)) << 4);
  u32 ldst = (u32)tid * 16;

  u32 aoff[4], boff[3];
#pragma unroll
  for (int mi = 0; mi < 4; mi++) {
    int r = wr * 64 + mi * 16 + lr;
    aoff[mi] = r * 128 + ((lq ^ (r & 7)) << 4);
  }
#pragma unroll
  for (int ni = 0; ni < 3; ni++) {
    int r = wc * 48 + ni * 16 + lr;
    boff[ni] = r * 128 + ((lq ^ (r & 7)) << 4);
  }

  const char* Bb = (const char*)wcat + (size_t)o0 * 2048;

  auto STAGE = [&](int buf, int step) {
    int t = step >> 3;
    u32 kb = (u32)(step & 7) * 128;
    const char* Ab = (const char*)xs + ((size_t)t * M2_ + m0) * 1024;
    char* L = lds + buf * 40960;
#pragma unroll
    for (int r2 = 0; r2 < 4; r2++)
      gl_lds16(Ab + (size_t)(r2 * 32 + srow) * 1024 + kb + sgoff, L + r2 * 4096 + ldst);
#pragma unroll
    for (int r2 = 0; r2 < 3; r2++) {
      gl_lds16(Bb + (size_t)(r2 * 32 + srow) * 2048 + kb + sgoff, L + 16384 + r2 * 4096 + ldst);
      gl_lds16(Bb + (size_t)(r2 * 32 + srow) * 2048 + 1024 + kb + sgoff, L + 28672 + r2 * 4096 + ldst);
    }
  };

  float vst[4][3][4];
#pragma unroll
  for (int a = 0; a < 4; a++)
#pragma unroll
    for (int b = 0; b < 3; b++)
#pragma unroll
      for (int c = 0; c < 4; c++) vst[a][b][c] = 0.f;

  f4 acc[4][3];
  STAGE(0, 0);
  int cur = 0;
  for (int step = 0; step < 32; ++step) {
    int ks = step & 7;
    if (ks == 0) {
#pragma unroll
      for (int a = 0; a < 4; a++)
#pragma unroll
        for (int b = 0; b < 3; b++) { acc[a][b][0] = 0.f; acc[a][b][1] = 0.f; acc[a][b][2] = 0.f; acc[a][b][3] = 0.f; }
    }
    if (step < 31) {
      STAGE(cur ^ 1, step + 1);
      asm volatile("s_waitcnt vmcnt(10)" ::: "memory");
    } else {
      asm volatile("s_waitcnt vmcnt(0)" ::: "memory");
    }
    __builtin_amdgcn_s_barrier();
    __builtin_amdgcn_sched_barrier(0);
    const char* L = lds + cur * 40960;
#pragma unroll
    for (int h = 0; h < 2; h++) {
      u32 hx = (u32)h << 6;
      bh8 af[4], bf[3], lf[3];
#pragma unroll
      for (int mi = 0; mi < 4; mi++)
        af[mi] = *(const bh8*)(L + (aoff[mi] ^ hx));
#pragma unroll
      for (int ni = 0; ni < 3; ni++) {
        bf[ni] = *(const bh8*)(L + 16384 + (boff[ni] ^ hx));
        lf[ni] = *(const bh8*)(L + 28672 + (boff[ni] ^ hx));
      }
#pragma unroll
      for (int mi = 0; mi < 4; mi++)
#pragma unroll
        for (int ni = 0; ni < 3; ni++)
          acc[mi][ni] = __builtin_amdgcn_mfma_f32_16x16x32_bf16(af[mi], bf[ni], acc[mi][ni], 0, 0, 0);
#pragma unroll
      for (int mi = 0; mi < 4; mi++)
#pragma unroll
        for (int ni = 0; ni < 3; ni++)
          acc[mi][ni] = __builtin_amdgcn_mfma_f32_16x16x32_bf16(af[mi], lf[ni], acc[mi][ni], 0, 0, 0);
    }
    if (ks == 7) {
      int t = step >> 3;
#pragma unroll
      for (int mi = 0; mi < 4; mi++)
#pragma unroll
        for (int ni = 0; ni < 3; ni++)
#pragma unroll
          for (int j = 0; j < 4; j++) {
            float y = acc[mi][ni][j];
            y = (y - mn[ni]) * scl[ni] + bt[ni];
            float vv = vst[mi][ni][j];
            vv = vv + (y - vv) * 0.5f;
            u16 s = 0;
            if (vv >= 1.0f) { s = 0x3F80; vv = 0.f; }
            vst[mi][ni][j] = vv;
            int r = wr * 64 + mi * 16 + lq * 4 + j;         // local row in [0,128)
            int rg = m0 + r;                                 // row in [0,M2)
            int o = o0 + wc * 48 + ni * 16 + lr;
            size_t rowg = (size_t)t * M2_ + rg;
            if (o < 512) {
              qs[rowg * 512 + o] = s;
            } else {
              kvsp[rowg * 1024 + (o - 512)] = s;
              if (o >= 1024) {
                int cq = o - 1024, hh = cq >> 6, d = cq & 63;
                int tb = (int)(rowg >> 8);
                int n = rg & 255;
                vout[(((size_t)tb * 8 + hh) * 256 + n) * 64 + d] = s ? 1.0f : 0.0f;
              }
            }
          }
    }
    __builtin_amdgcn_sched_barrier(0);
    __builtin_amdgcn_s_barrier();
    cur ^= 1;
  }
}

// ---------------- K3: kv-count partials (contiguous KVSP rows) ----------------
__global__ void k_kvv(const u16* __restrict__ kvsp, int* __restrict__ kvp) {
  int tb = blockIdx.x >> 3, nc = blockIdx.x & 7;
  int tid = threadIdx.x;
  const char* base = (const char*)kvsp + ((size_t)tb * 256 + nc * 32) * 2048;
  int c = tid * 2;
  int cnt0 = 0, cnt1 = 0;
  for (int n = 0; n < 32; n++) {
    u32 kk = *(const u32*)(base + (size_t)n * 2048 + c * 2);
    u32 vv = *(const u32*)(base + (size_t)n * 2048 + 1024 + c * 2);
    u32 a = kk & vv;
    cnt0 += (a & 0xFFFFu) ? 1 : 0;
    cnt1 += (a >> 16) ? 1 : 0;
  }
  kvp[((tb * 8 + nc) << 9) + c]     = cnt0;
  kvp[((tb * 8 + nc) << 9) + c + 1] = cnt1;
}

// ---------------- K4: talking-heads LIF (thresh 0.5) -> mask ----------------
__global__ void k_tlif(const int* __restrict__ kvp, unsigned char* __restrict__ mask) {
  int id = blockIdx.x * 256 + threadIdx.x;
  int b = id >> 9, c = id & 511;
  float v = 0.f;
  for (int t = 0; t < 4; t++) {
    int tb = t * 16 + b;
    int s = 0;
#pragma unroll
    for (int nc = 0; nc < 8; nc++) s += kvp[((tb * 8 + nc) << 9) + c];
    float xx = (float)s;
    v = v + (xx - v) * 0.5f;
    unsigned char sp = 0;
    if (v >= 0.5f) { sp = 1; v = 0.f; }
    mask[tb * 512 + c] = sp;
  }
}

// ---------------- K5: proj GEMM, counted-vmcnt dbuf, mask-AND + fused epilogue ----------------
// 128x64 tile, 8 steps, dbuf 2x32KB + lm 1KB.
__launch_bounds__(256, 2)
__global__ void k_proj_gemm(const u16* __restrict__ qs, const unsigned char* __restrict__ mask,
                            const u16* __restrict__ wpc, const float* __restrict__ pss,
                            const float* __restrict__ x, float* __restrict__ out) {
  __shared__ char lds[66560];   // buf: A 16K | Bh 8K | Bl 8K ; x2 = 64K ; lm at 65536
  u16* lm = (u16*)(lds + 65536);
  int tid = threadIdx.x, lane = tid & 63, wid = tid >> 6;
  int wr = wid >> 1, wc = wid & 1, lr = lane & 15, lq = lane >> 4;
  int m0 = blockIdx.x * 128, o0 = blockIdx.y * 64;
  int tb = m0 >> 8;

  lm[tid]       = mask[tb * 512 + tid]       ? (u16)0xFFFF : (u16)0;
  lm[tid + 256] = mask[tb * 512 + tid + 256] ? (u16)0xFFFF : (u16)0;

  int srow = tid >> 3;
  u32 sgoff = (u32)(((tid & 7) ^ (srow & 7)) << 4);
  u32 ldst = (u32)tid * 16;

  u32 aoff[4], boff[2];
#pragma unroll
  for (int mi = 0; mi < 4; mi++) {
    int r = wr * 64 + mi * 16 + lr;
    aoff[mi] = r * 128 + ((lq ^ (r & 7)) << 4);
  }
#pragma unroll
  for (int ni = 0; ni < 2; ni++) {
    int r = wc * 32 + ni * 16 + lr;
    boff[ni] = r * 128 + ((lq ^ (r & 7)) << 4);
  }

  const char* Ab = (const char*)qs + (size_t)m0 * 1024;
  const char* Bb = (const char*)wpc + (size_t)o0 * 2048;

  auto STAGE = [&](int buf, int step) {
    u32 kb = (u32)step * 128;
    char* L = lds + buf * 32768;
#pragma unroll
    for (int r2 = 0; r2 < 4; r2++)
      gl_lds16(Ab + (size_t)(r2 * 32 + srow) * 1024 + kb + sgoff, L + r2 * 4096 + ldst);
#pragma unroll
    for (int r2 = 0; r2 < 2; r2++) {
      gl_lds16(Bb + (size_t)(r2 * 32 + srow) * 2048 + kb + sgoff, L + 16384 + r2 * 4096 + ldst);
      gl_lds16(Bb + (size_t)(r2 * 32 + srow) * 2048 + 1024 + kb + sgoff, L + 24576 + r2 * 4096 + ldst);
    }
  };

  f4 acc[4][2];
#pragma unroll
  for (int a = 0; a < 4; a++)
#pragma unroll
    for (int b = 0; b < 2; b++) { acc[a][b][0] = 0.f; acc[a][b][1] = 0.f; acc[a][b][2] = 0.f; acc[a][b][3] = 0.f; }

  __syncthreads();            // lm visible to all waves
  STAGE(0, 0);
  int cur = 0;
  for (int step = 0; step < 8; ++step) {
    u32 kb = (u32)step * 128;
    if (step < 7) {
      STAGE(cur ^ 1, step + 1);
      asm volatile("s_waitcnt vmcnt(8)" ::: "memory");
    } else {
      asm volatile("s_waitcnt vmcnt(0)" ::: "memory");
    }
    __builtin_amdgcn_s_barrier();
    __builtin_amdgcn_sched_barrier(0);
    const char* L = lds + cur * 32768;
#pragma unroll
    for (int h = 0; h < 2; h++) {
      u32 hx = (u32)h << 6;
      bh8 mq = *(const bh8*)((const char*)lm + kb + (h << 6) + lq * 16);
      bh8 af[4], bf[2], lf[2];
#pragma unroll
      for (int mi = 0; mi < 4; mi++) {
        af[mi] = *(const bh8*)(L + (aoff[mi] ^ hx));
        af[mi] = af[mi] & mq;
      }
#pragma unroll
      for (int ni = 0; ni < 2; ni++) {
        bf[ni] = *(const bh8*)(L + 16384 + (boff[ni] ^ hx));
        lf[ni] = *(const bh8*)(L + 24576 + (boff[ni] ^ hx));
      }
#pragma unroll
      for (int mi = 0; mi < 4; mi++)
#pragma unroll
        for (int ni = 0; ni < 2; ni++)
          acc[mi][ni] = __builtin_amdgcn_mfma_f32_16x16x32_bf16(af[mi], bf[ni], acc[mi][ni], 0, 0, 0);
#pragma unroll
      for (int mi = 0; mi < 4; mi++)
#pragma unroll
        for (int ni = 0; ni < 2; ni++)
          acc[mi][ni] = __builtin_amdgcn_mfma_f32_16x16x32_bf16(af[mi], lf[ni], acc[mi][ni], 0, 0, 0);
    }
    __builtin_amdgcn_sched_barrier(0);
    __builtin_amdgcn_s_barrier();
    cur ^= 1;
  }
  // fused epilogue: BN(y + bp) + identity, transposed store to out[tb][o][n]
#pragma unroll
  for (int mi = 0; mi < 4; mi++)
#pragma unroll
    for (int ni = 0; ni < 2; ni++) {
      int o = o0 + wc * 32 + ni * 16 + lr;
      f4 ps = *(const f4*)&pss[o * 4];        // {bp, pm, scale, beta}
      int n = (m0 & 255) + wr * 64 + mi * 16 + lq * 4;
      size_t idx = (size_t)tb * 131072 + (size_t)o * 256 + n;
      f4 xv = *(const f4*)&x[idx];
      f4 res;
#pragma unroll
      for (int j = 0; j < 4; j++) {
        float u = acc[mi][ni][j] + ps[0];
        u = (u - ps[1]) * ps[2] + ps[3];
        res[j] = u + xv[j];
      }
      *(f4*)&out[idx] = res;
    }
}

// ---------------- launch ----------------
extern "C" void kernel_launch(void* const* d_in, const int* in_sizes, int n_in,
                              void* d_out, int out_size, void* d_ws, size_t ws_size,
                              hipStream_t stream) {
  const float* x  = (const float*)d_in[0];
  const float* wq = (const float*)d_in[1];
  const float* qg = (const float*)d_in[2];
  const float* qb = (const float*)d_in[3];
  const float* qm = (const float*)d_in[4];
  const float* qv = (const float*)d_in[5];
  const float* wk = (const float*)d_in[6];
  const float* kg = (const float*)d_in[7];
  const float* kb = (const float*)d_in[8];
  const float* km = (const float*)d_in[9];
  const float* kv = (const float*)d_in[10];
  const float* wv = (const float*)d_in[11];
  const float* vg = (const float*)d_in[12];
  const float* vb = (const float*)d_in[13];
  const float* vm = (const float*)d_in[14];
  const float* vv = (const float*)d_in[15];
  const float* wp = (const float*)d_in[16];
  const float* bp = (const float*)d_in[17];
  const float* pg = (const float*)d_in[18];
  const float* pb = (const float*)d_in[19];
  const float* pm = (const float*)d_in[20];
  const float* pv = (const float*)d_in[21];

  char* w = (char*)d_ws;
  u16*  XS    = (u16*)(w + 0);                    // 16 MiB (T,B,N,C) bf16
  u16*  QS    = (u16*)(w + 16777216);             // 16 MiB (T*M2, 512) q spikes
  u16*  KVSP  = (u16*)(w + 33554432);             // 32 MiB (T*M2, 1024) k|v spikes
  u16*  WCAT  = (u16*)(w + 67108864);             // 3 MiB
  u16*  WPCAT = (u16*)(w + 70254592);             // 1 MiB
  float* BNS  = (float*)(w + 71303168);           // 24 KiB
  float* PSS  = (float*)(w + 71327744);           // 8 KiB
  int*   KVP  = (int*)(w + 71335936);             // 1 MiB
  unsigned char* MASK = (unsigned char*)(w + 72384512); // 32 KiB

  float* out  = (float*)d_out;                    // (T,B,C,N) f32
  float* vout = out + 8388608;                    // (T,B,8,N,64) f32

  k_prep<<<4104, 256, 0, stream>>>(wq, wk, wv, wp, qg, qb, qm, qv, kg, kb, km, kv,
                                   vg, vb, vm, vv, pg, pb, pm, pv, bp,
                                   WCAT, WPCAT, BNS, PSS);
  k_lif_x<<<dim3(4, 8, 16), 256, 0, stream>>>(x, XS);
  k_qkv_gemm<<<dim3(32, 16), 256, 0, stream>>>(XS, WCAT, BNS, QS, KVSP, vout);
  k_kvv<<<512, 256, 0, stream>>>(KVSP, KVP);
  k_tlif<<<32, 256, 0, stream>>>(KVP, MASK);
  k_proj_gemm<<<dim3(128, 8), 256, 0, stream>>>(QS, MASK, WPCAT, PSS, x, out);
}

// Round 4
// 213.661 us; speedup vs baseline: 1.1620x; 1.1620x over previous
//
#include <hip/hip_runtime.h>
#include <hip/hip_bf16.h>

typedef unsigned short u16;
typedef unsigned int u32;
typedef __attribute__((ext_vector_type(8))) short bh8;   // 8 bf16 (MFMA A/B frag)
typedef __attribute__((ext_vector_type(4))) short sh4;   // 4 bf16 (8B store)
typedef __attribute__((ext_vector_type(4))) float f4;    // MFMA C/D frag

#define T_   4
#define B_   16
#define C_   512
#define N_   256
#define M2_  4096

// ---------------- helpers ----------------
__device__ __forceinline__ u16 f2bf(float f) {
  u32 u = __float_as_uint(f);
  u32 r = (u + 0x7FFFu + ((u >> 16) & 1u)) >> 16;   // RNE
  return (u16)r;
}
__device__ __forceinline__ void gl_lds16(const void* g, void* l) {
  __builtin_amdgcn_global_load_lds(
      (const __attribute__((address_space(1))) unsigned int*)g,
      (__attribute__((address_space(3))) unsigned int*)l, 16, 0, 0);
}

// ---------------- K0: merged {weight hi/lo split + BN consts} + {shortcut LIF} ----------------
// blocks [0,512): LIF over x + (c,n)->(n,c) transpose to bf16 spikes
// blocks [512,4616): weight split + BN constant prep
__global__ void k_prep_lif(const float* __restrict__ x, u16* __restrict__ xs,
                           const float* __restrict__ wq, const float* __restrict__ wk,
                           const float* __restrict__ wv, const float* __restrict__ wp,
                           const float* qg, const float* qb, const float* qm, const float* qv,
                           const float* kg, const float* kb, const float* km, const float* kv2,
                           const float* vg, const float* vb, const float* vm, const float* vv,
                           const float* pg, const float* pb, const float* pm, const float* pv,
                           const float* bp,
                           u16* __restrict__ wcat, u16* __restrict__ wpcat,
                           float* bns, float* pss) {
  __shared__ u16 sp[4][64][68];
  int bid = blockIdx.x;
  int tid = threadIdx.x;
  if (bid < 512) {
    int b = bid >> 5, c0 = ((bid >> 2) & 7) * 64, n0 = (bid & 3) * 64;
    int rq = tid >> 4;
    int n4 = (tid & 15) * 4;
    float v[16];
#pragma unroll
    for (int i = 0; i < 16; i++) v[i] = 0.f;
    for (int t = 0; t < 4; t++) {
      const float* xb = x + (((size_t)t * 16 + b) * 512 + c0) * 256 + n0;
#pragma unroll
      for (int i = 0; i < 4; i++) {
        int row = rq + i * 16;
        f4 xv = *(const f4*)(xb + (size_t)row * 256 + n4);
        sh4 sv;
#pragma unroll
        for (int j = 0; j < 4; j++) {
          float vv2 = v[i * 4 + j];
          vv2 = vv2 + (xv[j] - vv2) * 0.5f;
          u16 s = 0;
          if (vv2 >= 1.0f) { s = 0x3F80; vv2 = 0.f; }
          v[i * 4 + j] = vv2;
          sv[j] = (short)s;
        }
        *(sh4*)&sp[t][row][n4] = sv;
      }
    }
    __syncthreads();
    int cp = (tid & 31) * 2;
    int nq = tid >> 5;
    for (int t = 0; t < 4; t++) {
      u16* ob = xs + (((size_t)t * 16 + b) * 256 + n0) * 512 + c0;
#pragma unroll
      for (int i = 0; i < 8; i++) {
        int n = nq + i * 8;
        u32 w = (u32)sp[t][cp][n] | ((u32)sp[t][cp + 1][n] << 16);
        *(u32*)(ob + (size_t)n * 512 + cp) = w;
      }
    }
  } else {
    int id = (bid - 512) * 256 + tid;
    if (id < 1048576) {
      int mat = id >> 18;
      int rc  = id & 262143;
      int o = rc >> 9, c = rc & 511;
      const float* src = (mat == 0) ? wq : (mat == 1) ? wk : (mat == 2) ? wv : wp;
      float w = src[rc];
      u16 hu = f2bf(w);
      float hf = __uint_as_float(((u32)hu) << 16);
      u16 lu = f2bf(w - hf);
      if (mat < 3) {
        size_t base = ((size_t)(mat * 512 + o)) * 1024 + c;
        wcat[base] = hu; wcat[base + 512] = lu;
      } else {
        size_t base = (size_t)o * 1024 + c;
        wpcat[base] = hu; wpcat[base + 512] = lu;
      }
    } else {
      int j = id - 1048576;
      if (j < 1536) {
        int br = j >> 9, c = j & 511;
        const float *g, *b, *m, *va;
        if (br == 0)      { g = qg; b = qb; m = qm; va = qv; }
        else if (br == 1) { g = kg; b = kb; m = km; va = kv2; }
        else              { g = vg; b = vb; m = vm; va = vv; }
        float s = g[c] / sqrtf(va[c] + 1e-5f);
        bns[j * 4 + 0] = s; bns[j * 4 + 1] = m[c]; bns[j * 4 + 2] = b[c];
        bns[j * 4 + 3] = 0.f;
      } else if (j < 2048) {
        int c = j - 1536;
        float s = pg[c] / sqrtf(pv[c] + 1e-5f);
        pss[c * 4 + 0] = bp[c]; pss[c * 4 + 1] = pm[c];
        pss[c * 4 + 2] = s;     pss[c * 4 + 3] = pb[c];
      }
    }
  }
}

// ---------------- K2: fused QKV GEMM + BN + LIF, T3-minimum pipeline ----------------
// 128x96 tile, BK=64, 32 flattened (t,ks) steps, dbuf 2x40KB, one barrier/step.
__launch_bounds__(256, 2)
__global__ void k_qkv_gemm(const u16* __restrict__ xs, const u16* __restrict__ wcat,
                           const float* __restrict__ bns,
                           u16* __restrict__ qs, u16* __restrict__ kvsp) {
  __shared__ char lds[81920];   // buf: A 16K | Bh 12K | Bl 12K ; x2
  int tid = threadIdx.x, lane = tid & 63, wid = tid >> 6;
  int wr = wid >> 1, wc = wid & 1, lr = lane & 15, lq = lane >> 4;
  int m0 = blockIdx.x * 128, o0 = blockIdx.y * 96;

  float scl[3], mn[3], bt[3];
#pragma unroll
  for (int ni = 0; ni < 3; ni++) {
    int ch = o0 + wc * 48 + ni * 16 + lr;
    scl[ni] = bns[ch * 4]; mn[ni] = bns[ch * 4 + 1]; bt[ni] = bns[ch * 4 + 2];
  }

  int srow = tid >> 3;
  u32 sgoff = (u32)(((tid & 7) ^ (srow & 7)) << 4);
  u32 ldst = (u32)tid * 16;

  u32 aoff[4], boff[3];
#pragma unroll
  for (int mi = 0; mi < 4; mi++) {
    int r = wr * 64 + mi * 16 + lr;
    aoff[mi] = r * 128 + ((lq ^ (r & 7)) << 4);
  }
#pragma unroll
  for (int ni = 0; ni < 3; ni++) {
    int r = wc * 48 + ni * 16 + lr;
    boff[ni] = r * 128 + ((lq ^ (r & 7)) << 4);
  }

  const char* Bb = (const char*)wcat + (size_t)o0 * 2048;

  auto STAGE = [&](int buf, int step) {
    int t = step >> 3;
    u32 kb = (u32)(step & 7) * 128;
    const char* Ab = (const char*)xs + ((size_t)t * M2_ + m0) * 1024;
    char* L = lds + buf * 40960;
#pragma unroll
    for (int r2 = 0; r2 < 4; r2++)
      gl_lds16(Ab + (size_t)(r2 * 32 + srow) * 1024 + kb + sgoff, L + r2 * 4096 + ldst);
#pragma unroll
    for (int r2 = 0; r2 < 3; r2++) {
      gl_lds16(Bb + (size_t)(r2 * 32 + srow) * 2048 + kb + sgoff, L + 16384 + r2 * 4096 + ldst);
      gl_lds16(Bb + (size_t)(r2 * 32 + srow) * 2048 + 1024 + kb + sgoff, L + 28672 + r2 * 4096 + ldst);
    }
  };

  float vst[4][3][4];
#pragma unroll
  for (int a = 0; a < 4; a++)
#pragma unroll
    for (int b = 0; b < 3; b++)
#pragma unroll
      for (int c = 0; c < 4; c++) vst[a][b][c] = 0.f;

  f4 acc[4][3];
  STAGE(0, 0);
  __syncthreads();                 // drain prologue stage
  int cur = 0;
  for (int step = 0; step < 32; ++step) {
    int ks = step & 7;
    if (ks == 0) {
#pragma unroll
      for (int a = 0; a < 4; a++)
#pragma unroll
        for (int b = 0; b < 3; b++) { acc[a][b][0] = 0.f; acc[a][b][1] = 0.f; acc[a][b][2] = 0.f; acc[a][b][3] = 0.f; }
    }
    if (step < 31) STAGE(cur ^ 1, step + 1);   // next-tile loads in flight across MFMAs
    const char* L = lds + cur * 40960;
#pragma unroll
    for (int h = 0; h < 2; h++) {
      u32 hx = (u32)h << 6;
      bh8 af[4], bf[3], lf[3];
#pragma unroll
      for (int mi = 0; mi < 4; mi++)
        af[mi] = *(const bh8*)(L + (aoff[mi] ^ hx));
#pragma unroll
      for (int ni = 0; ni < 3; ni++) {
        bf[ni] = *(const bh8*)(L + 16384 + (boff[ni] ^ hx));
        lf[ni] = *(const bh8*)(L + 28672 + (boff[ni] ^ hx));
      }
#pragma unroll
      for (int mi = 0; mi < 4; mi++)
#pragma unroll
        for (int ni = 0; ni < 3; ni++)
          acc[mi][ni] = __builtin_amdgcn_mfma_f32_16x16x32_bf16(af[mi], bf[ni], acc[mi][ni], 0, 0, 0);
#pragma unroll
      for (int mi = 0; mi < 4; mi++)
#pragma unroll
        for (int ni = 0; ni < 3; ni++)
          acc[mi][ni] = __builtin_amdgcn_mfma_f32_16x16x32_bf16(af[mi], lf[ni], acc[mi][ni], 0, 0, 0);
    }
    asm volatile("s_waitcnt vmcnt(0)" ::: "memory");   // next-tile loads landed
    __builtin_amdgcn_s_barrier();
    cur ^= 1;
    // BN + LIF epilogue AFTER barrier: stores drain under next step's compute
    if (ks == 7) {
      int t = step >> 3;
#pragma unroll
      for (int mi = 0; mi < 4; mi++)
#pragma unroll
        for (int ni = 0; ni < 3; ni++)
#pragma unroll
          for (int j = 0; j < 4; j++) {
            float y = acc[mi][ni][j];
            y = (y - mn[ni]) * scl[ni] + bt[ni];
            float vv = vst[mi][ni][j];
            vv = vv + (y - vv) * 0.5f;
            u16 s = 0;
            if (vv >= 1.0f) { s = 0x3F80; vv = 0.f; }
            vst[mi][ni][j] = vv;
            int rg = m0 + wr * 64 + mi * 16 + lq * 4 + j;
            int o = o0 + wc * 48 + ni * 16 + lr;
            size_t rowg = (size_t)t * M2_ + rg;
            if (o < 512) qs[rowg * 512 + o] = s;
            else         kvsp[rowg * 1024 + (o - 512)] = s;
          }
    }
  }
}

// ---------------- K3: kv-count partials + v-spike f32 output (line-dense) ----------------
__global__ void k_kvv(const u16* __restrict__ kvsp, float* __restrict__ vout,
                      int* __restrict__ kvp) {
  int tb = blockIdx.x >> 3, nc = blockIdx.x & 7;
  int tid = threadIdx.x;
  const char* base = (const char*)kvsp + ((size_t)tb * 256 + nc * 32) * 2048;
  int c = tid * 2, h = c >> 6, d = c & 63;
  float* vo = vout + (((size_t)tb * 8 + h) * 256 + nc * 32) * 64 + d;
  int cnt0 = 0, cnt1 = 0;
  for (int n = 0; n < 32; n++) {
    u32 kk = *(const u32*)(base + (size_t)n * 2048 + c * 2);
    u32 vv = *(const u32*)(base + (size_t)n * 2048 + 1024 + c * 2);
    u32 a = kk & vv;
    cnt0 += (a & 0xFFFFu) ? 1 : 0;
    cnt1 += (a >> 16) ? 1 : 0;
    float2 w;
    w.x = (vv & 0xFFFFu) ? 1.f : 0.f;
    w.y = (vv >> 16) ? 1.f : 0.f;
    *(float2*)(vo + (size_t)n * 64) = w;
  }
  kvp[((tb * 8 + nc) << 9) + c]     = cnt0;
  kvp[((tb * 8 + nc) << 9) + c + 1] = cnt1;
}

// ---------------- K4: talking-heads LIF (thresh 0.5) -> mask ----------------
__global__ void k_tlif(const int* __restrict__ kvp, unsigned char* __restrict__ mask) {
  int id = blockIdx.x * 256 + threadIdx.x;
  int b = id >> 9, c = id & 511;
  float v = 0.f;
  for (int t = 0; t < 4; t++) {
    int tb = t * 16 + b;
    int s = 0;
#pragma unroll
    for (int nc = 0; nc < 8; nc++) s += kvp[((tb * 8 + nc) << 9) + c];
    float xx = (float)s;
    v = v + (xx - v) * 0.5f;
    unsigned char sp = 0;
    if (v >= 0.5f) { sp = 1; v = 0.f; }
    mask[tb * 512 + c] = sp;
  }
}

// ---------------- K5: proj GEMM, T3-minimum pipeline, mask-AND + fused epilogue ----------------
// 128x64 tile, 8 steps, dbuf 2x32KB + lm 1KB.
__launch_bounds__(256, 2)
__global__ void k_proj_gemm(const u16* __restrict__ qs, const unsigned char* __restrict__ mask,
                            const u16* __restrict__ wpc, const float* __restrict__ pss,
                            const float* __restrict__ x, float* __restrict__ out) {
  __shared__ char lds[66560];   // buf: A 16K | Bh 8K | Bl 8K ; x2 = 64K ; lm at 65536
  u16* lm = (u16*)(lds + 65536);
  int tid = threadIdx.x, lane = tid & 63, wid = tid >> 6;
  int wr = wid >> 1, wc = wid & 1, lr = lane & 15, lq = lane >> 4;
  int m0 = blockIdx.x * 128, o0 = blockIdx.y * 64;
  int tb = m0 >> 8;

  lm[tid]       = mask[tb * 512 + tid]       ? (u16)0xFFFF : (u16)0;
  lm[tid + 256] = mask[tb * 512 + tid + 256] ? (u16)0xFFFF : (u16)0;

  int srow = tid >> 3;
  u32 sgoff = (u32)(((tid & 7) ^ (srow & 7)) << 4);
  u32 ldst = (u32)tid * 16;

  u32 aoff[4], boff[2];
#pragma unroll
  for (int mi = 0; mi < 4; mi++) {
    int r = wr * 64 + mi * 16 + lr;
    aoff[mi] = r * 128 + ((lq ^ (r & 7)) << 4);
  }
#pragma unroll
  for (int ni = 0; ni < 2; ni++) {
    int r = wc * 32 + ni * 16 + lr;
    boff[ni] = r * 128 + ((lq ^ (r & 7)) << 4);
  }

  const char* Ab = (const char*)qs + (size_t)m0 * 1024;
  const char* Bb = (const char*)wpc + (size_t)o0 * 2048;

  auto STAGE = [&](int buf, int step) {
    u32 kb = (u32)step * 128;
    char* L = lds + buf * 32768;
#pragma unroll
    for (int r2 = 0; r2 < 4; r2++)
      gl_lds16(Ab + (size_t)(r2 * 32 + srow) * 1024 + kb + sgoff, L + r2 * 4096 + ldst);
#pragma unroll
    for (int r2 = 0; r2 < 2; r2++) {
      gl_lds16(Bb + (size_t)(r2 * 32 + srow) * 2048 + kb + sgoff, L + 16384 + r2 * 4096 + ldst);
      gl_lds16(Bb + (size_t)(r2 * 32 + srow) * 2048 + 1024 + kb + sgoff, L + 24576 + r2 * 4096 + ldst);
    }
  };

  f4 acc[4][2];
#pragma unroll
  for (int a = 0; a < 4; a++)
#pragma unroll
    for (int b = 0; b < 2; b++) { acc[a][b][0] = 0.f; acc[a][b][1] = 0.f; acc[a][b][2] = 0.f; acc[a][b][3] = 0.f; }

  STAGE(0, 0);
  __syncthreads();                 // drain prologue stage + publish lm
  int cur = 0;
  for (int step = 0; step < 8; ++step) {
    u32 kb = (u32)step * 128;
    if (step < 7) STAGE(cur ^ 1, step + 1);
    const char* L = lds + cur * 32768;
#pragma unroll
    for (int h = 0; h < 2; h++) {
      u32 hx = (u32)h << 6;
      bh8 mq = *(const bh8*)((const char*)lm + kb + (h << 6) + lq * 16);
      bh8 af[4], bf[2], lf[2];
#pragma unroll
      for (int mi = 0; mi < 4; mi++) {
        af[mi] = *(const bh8*)(L + (aoff[mi] ^ hx));
        af[mi] = af[mi] & mq;
      }
#pragma unroll
      for (int ni = 0; ni < 2; ni++) {
        bf[ni] = *(const bh8*)(L + 16384 + (boff[ni] ^ hx));
        lf[ni] = *(const bh8*)(L + 24576 + (boff[ni] ^ hx));
      }
#pragma unroll
      for (int mi = 0; mi < 4; mi++)
#pragma unroll
        for (int ni = 0; ni < 2; ni++)
          acc[mi][ni] = __builtin_amdgcn_mfma_f32_16x16x32_bf16(af[mi], bf[ni], acc[mi][ni], 0, 0, 0);
#pragma unroll
      for (int mi = 0; mi < 4; mi++)
#pragma unroll
        for (int ni = 0; ni < 2; ni++)
          acc[mi][ni] = __builtin_amdgcn_mfma_f32_16x16x32_bf16(af[mi], lf[ni], acc[mi][ni], 0, 0, 0);
    }
    asm volatile("s_waitcnt vmcnt(0)" ::: "memory");
    __builtin_amdgcn_s_barrier();
    cur ^= 1;
  }
  // fused epilogue: BN(y + bp) + identity, transposed store to out[tb][o][n]
#pragma unroll
  for (int mi = 0; mi < 4; mi++)
#pragma unroll
    for (int ni = 0; ni < 2; ni++) {
      int o = o0 + wc * 32 + ni * 16 + lr;
      f4 ps = *(const f4*)&pss[o * 4];        // {bp, pm, scale, beta}
      int n = (m0 & 255) + wr * 64 + mi * 16 + lq * 4;
      size_t idx = (size_t)tb * 131072 + (size_t)o * 256 + n;
      f4 xv = *(const f4*)&x[idx];
      f4 res;
#pragma unroll
      for (int j = 0; j < 4; j++) {
        float u = acc[mi][ni][j] + ps[0];
        u = (u - ps[1]) * ps[2] + ps[3];
        res[j] = u + xv[j];
      }
      *(f4*)&out[idx] = res;
    }
}

// ---------------- launch ----------------
extern "C" void kernel_launch(void* const* d_in, const int* in_sizes, int n_in,
                              void* d_out, int out_size, void* d_ws, size_t ws_size,
                              hipStream_t stream) {
  const float* x  = (const float*)d_in[0];
  const float* wq = (const float*)d_in[1];
  const float* qg = (const float*)d_in[2];
  const float* qb = (const float*)d_in[3];
  const float* qm = (const float*)d_in[4];
  const float* qv = (const float*)d_in[5];
  const float* wk = (const float*)d_in[6];
  const float* kg = (const float*)d_in[7];
  const float* kb = (const float*)d_in[8];
  const float* km = (const float*)d_in[9];
  const float* kv = (const float*)d_in[10];
  const float* wv = (const float*)d_in[11];
  const float* vg = (const float*)d_in[12];
  const float* vb = (const float*)d_in[13];
  const float* vm = (const float*)d_in[14];
  const float* vv = (const float*)d_in[15];
  const float* wp = (const float*)d_in[16];
  const float* bp = (const float*)d_in[17];
  const float* pg = (const float*)d_in[18];
  const float* pb = (const float*)d_in[19];
  const float* pm = (const float*)d_in[20];
  const float* pv = (const float*)d_in[21];

  char* w = (char*)d_ws;
  u16*  XS    = (u16*)(w + 0);                    // 16 MiB (T,B,N,C) bf16
  u16*  QS    = (u16*)(w + 16777216);             // 16 MiB (T*M2, 512) q spikes
  u16*  KVSP  = (u16*)(w + 33554432);             // 32 MiB (T*M2, 1024) k|v spikes
  u16*  WCAT  = (u16*)(w + 67108864);             // 3 MiB
  u16*  WPCAT = (u16*)(w + 70254592);             // 1 MiB
  float* BNS  = (float*)(w + 71303168);           // 24 KiB
  float* PSS  = (float*)(w + 71327744);           // 8 KiB
  int*   KVP  = (int*)(w + 71335936);             // 1 MiB
  unsigned char* MASK = (unsigned char*)(w + 72384512); // 32 KiB

  float* out  = (float*)d_out;                    // (T,B,C,N) f32
  float* vout = out + 8388608;                    // (T,B,8,N,64) f32

  k_prep_lif<<<4616, 256, 0, stream>>>(x, XS, wq, wk, wv, wp,
                                       qg, qb, qm, qv, kg, kb, km, kv,
                                       vg, vb, vm, vv, pg, pb, pm, pv, bp,
                                       WCAT, WPCAT, BNS, PSS);
  k_qkv_gemm<<<dim3(32, 16), 256, 0, stream>>>(XS, WCAT, BNS, QS, KVSP);
  k_kvv<<<512, 256, 0, stream>>>(KVSP, vout, KVP);
  k_tlif<<<32, 256, 0, stream>>>(KVP, MASK);
  k_proj_gemm<<<dim3(128, 8), 256, 0, stream>>>(QS, MASK, WPCAT, PSS, x, out);
}